// Round 1
// baseline (896.802 us; speedup 1.0000x reference)
//
#include <hip/hip_runtime.h>
#include <math.h>

#define VOCAB 50000
#define EMB   100
#define BATCH 2048
#define CTX   10

#define BT 128   // batch tile
#define VT 128   // vocab tile
#define BK 32    // k chunk (EMB = 32+32+32+4)

// ---------------- init: zero neg_sum[BATCH] and out[1] ----------------
__global__ void k_init(float* __restrict__ neg_sum, float* __restrict__ out) {
    int i = blockIdx.x * 256 + threadIdx.x;
    if (i < BATCH) neg_sum[i] = 0.0f;
    if (i == 0) out[0] = 0.0f;
}

// ---------------- h[b][e] = mean_c emb_v[x[b][c]][e] ----------------
__global__ void k_h(const int* __restrict__ x, const float* __restrict__ emb_v,
                    float* __restrict__ h) {
    int b = blockIdx.x;
    int e = threadIdx.x;
    if (e >= EMB) return;
    float s = 0.0f;
#pragma unroll
    for (int c = 0; c < CTX; ++c) {
        int idx = x[b * CTX + c];
        s += emb_v[idx * EMB + e];
    }
    h[b * EMB + e] = s * (1.0f / CTX);
}

// ---------------- fused GEMM + sigmoid row-sum ----------------
// C[b][v] = dot(h[b], u[v]); accumulate sum_v sigmoid(-C[b][v]) into neg_sum[b]
#define K_STEP(k)  do {                                                        \
      const float4 h0 = *(const float4*)&hs[k][ty * 4];                        \
      const float4 h1 = *(const float4*)&hs[k][64 + ty * 4];                   \
      const float4 u0 = *(const float4*)&us[k][tx * 4];                        \
      const float4 u1 = *(const float4*)&us[k][64 + tx * 4];                   \
      const float ha[8] = {h0.x, h0.y, h0.z, h0.w, h1.x, h1.y, h1.z, h1.w};    \
      const float ua[8] = {u0.x, u0.y, u0.z, u0.w, u1.x, u1.y, u1.z, u1.w};    \
      _Pragma("unroll") for (int i = 0; i < 8; ++i)                            \
        _Pragma("unroll") for (int j = 0; j < 8; ++j)                          \
          acc[i][j] = fmaf(ha[i], ua[j], acc[i][j]);                           \
    } while (0)

__launch_bounds__(256, 4)
__global__ void k_neg(const float* __restrict__ h, const float* __restrict__ u,
                      float* __restrict__ neg_sum) {
    __shared__ float hs[BK][BT];  // k-major to keep compute reads contiguous in b
    __shared__ float us[BK][VT];

    const int b0 = blockIdx.x * BT;
    const int v0 = blockIdx.y * VT;
    const int t  = threadIdx.x;
    const int tx = t & 15;
    const int ty = t >> 4;
    const int lq = t & 7;   // k-quad for staging
    const int lr = t >> 3;  // row for staging (0..31)

    float acc[8][8];
#pragma unroll
    for (int i = 0; i < 8; ++i)
#pragma unroll
        for (int j = 0; j < 8; ++j) acc[i][j] = 0.0f;

    for (int k0 = 0; k0 < EMB; k0 += BK) {
        const int klen = (EMB - k0 >= BK) ? BK : (EMB - k0);  // 32,32,32,4
        // ---- stage h-tile and u-tile (transpose to k-major) ----
        if (4 * lq + 4 <= klen) {
#pragma unroll
            for (int i = 0; i < 4; ++i) {
                const int r = lr + 32 * i;
                const float4 hv = *(const float4*)&h[(b0 + r) * EMB + k0 + 4 * lq];
                hs[4 * lq + 0][r] = hv.x;
                hs[4 * lq + 1][r] = hv.y;
                hs[4 * lq + 2][r] = hv.z;
                hs[4 * lq + 3][r] = hv.w;
                const int v = v0 + r;
                float4 uv = make_float4(0.f, 0.f, 0.f, 0.f);
                if (v < VOCAB) uv = *(const float4*)&u[v * EMB + k0 + 4 * lq];
                us[4 * lq + 0][r] = uv.x;
                us[4 * lq + 1][r] = uv.y;
                us[4 * lq + 2][r] = uv.z;
                us[4 * lq + 3][r] = uv.w;
            }
        }
        __syncthreads();
        // ---- compute ----
        if (klen == BK) {
#pragma unroll
            for (int k = 0; k < BK; ++k) { K_STEP(k); }
        } else {
            for (int k = 0; k < klen; ++k) { K_STEP(k); }
        }
        __syncthreads();
    }

    // ---- epilogue: sigmoid(-score) row sums ----
#pragma unroll
    for (int i = 0; i < 8; ++i) {
        const int b = b0 + ((i < 4) ? (ty * 4 + i) : (64 + ty * 4 + (i - 4)));
        float p = 0.0f;
#pragma unroll
        for (int j = 0; j < 8; ++j) {
            const int v = v0 + ((j < 4) ? (tx * 4 + j) : (64 + tx * 4 + (j - 4)));
            if (v < VOCAB) {
                // sigmoid(-s) = 1 / (1 + exp(s))
                p += 1.0f / (1.0f + __expf(acc[i][j]));
            }
        }
        // reduce across the 16 tx lanes (contiguous lanes share ty)
#pragma unroll
        for (int off = 8; off; off >>= 1) p += __shfl_down(p, off, 16);
        if (tx == 0) atomicAdd(&neg_sum[b], p);
    }
}

// ---------------- final: pos term + log(neg_sum) + mean ----------------
__global__ void k_final(const int* __restrict__ y, const float* __restrict__ h,
                        const float* __restrict__ u, const float* __restrict__ neg_sum,
                        float* __restrict__ out) {
    const int b = blockIdx.x * 64 + threadIdx.x;
    const int yi = y[b];
    const float4* hp = (const float4*)&h[b * EMB];
    const float4* up = (const float4*)&u[yi * EMB];
    float dot = 0.0f;
#pragma unroll
    for (int q = 0; q < EMB / 4; ++q) {
        const float4 a = hp[q];
        const float4 c = up[q];
        dot += a.x * c.x + a.y * c.y + a.z * c.z + a.w * c.w;
    }
    // pos = -log_sigmoid(dot) = softplus(-dot), numerically stable
    const float pos = fmaxf(-dot, 0.0f) + log1pf(__expf(-fabsf(dot)));
    float val = pos + logf(neg_sum[b]);
#pragma unroll
    for (int off = 32; off; off >>= 1) val += __shfl_down(val, off, 64);
    if (threadIdx.x == 0) atomicAdd(out, val * (1.0f / BATCH));
}

extern "C" void kernel_launch(void* const* d_in, const int* in_sizes, int n_in,
                              void* d_out, int out_size, void* d_ws, size_t ws_size,
                              hipStream_t stream) {
    const int*   x     = (const int*)d_in[0];
    const int*   y     = (const int*)d_in[1];
    const float* emb_v = (const float*)d_in[2];
    const float* emb_u = (const float*)d_in[3];
    float* out = (float*)d_out;

    float* h       = (float*)d_ws;                 // BATCH*EMB floats
    float* neg_sum = h + BATCH * EMB;              // BATCH floats

    k_init<<<dim3((BATCH + 255) / 256), dim3(256), 0, stream>>>(neg_sum, out);
    k_h<<<dim3(BATCH), dim3(128), 0, stream>>>(x, emb_v, h);
    k_neg<<<dim3(BATCH / BT, (VOCAB + VT - 1) / VT), dim3(256), 0, stream>>>(h, emb_u, neg_sum);
    k_final<<<dim3(BATCH / 64), dim3(64), 0, stream>>>(y, h, emb_u, neg_sum, out);
}

// Round 2
// 191.468 us; speedup vs baseline: 4.6838x; 4.6838x over previous
//
#include <hip/hip_runtime.h>
#include <math.h>

#define VOCAB 50000
#define EMB   100
#define KP    128      // K padded for MFMA
#define BATCH 2048
#define CTX   10

#define NVT   391      // number of 128-wide vocab tiles (391*128 = 50048)
#define BC    4        // batch chunks (grid.x)
#define BT    128      // batch tile per inner iteration

typedef __attribute__((ext_vector_type(8))) short short8;
typedef __attribute__((ext_vector_type(4))) float f32x4;

__device__ __forceinline__ unsigned short f2bf(float x) {
    union { float f; unsigned u; } v; v.f = x;
    unsigned r = (v.u + 0x7FFFu + ((v.u >> 16) & 1u)) >> 16;  // RNE
    return (unsigned short)r;
}

// ---------------- zero the scalar output ----------------
__global__ void k_init(float* __restrict__ out) {
    if (threadIdx.x == 0) out[0] = 0.0f;
}

// ---------------- emb_u fp32 [50000][100] -> bf16 [50048][128] zero-padded ----------------
__global__ void k_cvt_u(const float* __restrict__ u, unsigned short* __restrict__ ub) {
    const int c   = blockIdx.x * 256 + threadIdx.x;   // 800768 16B-chunks
    const int row = c >> 4;
    const int kb  = (c & 15) * 8;
    short8 o;
    if (row < VOCAB && kb + 8 <= EMB) {
        const float4* p = (const float4*)&u[row * EMB + kb];   // 16B-aligned (row*400 + kb*4)
        const float4 v0 = p[0], v1 = p[1];
        o[0] = (short)f2bf(v0.x); o[1] = (short)f2bf(v0.y);
        o[2] = (short)f2bf(v0.z); o[3] = (short)f2bf(v0.w);
        o[4] = (short)f2bf(v1.x); o[5] = (short)f2bf(v1.y);
        o[6] = (short)f2bf(v1.z); o[7] = (short)f2bf(v1.w);
    } else {
#pragma unroll
        for (int j = 0; j < 8; ++j) {
            const int k = kb + j;
            const float val = (row < VOCAB && k < EMB) ? u[row * EMB + k] : 0.0f;
            o[j] = (short)f2bf(val);
        }
    }
    *(short8*)&ub[row * KP + kb] = o;
}

// ---------------- h = mean of context embeddings; fp32 (for pos term) + bf16 padded ----------------
__global__ void k_h(const int* __restrict__ x, const float* __restrict__ emb_v,
                    float* __restrict__ hf, unsigned short* __restrict__ hb) {
    const int b = blockIdx.x;
    const int e = threadIdx.x;  // 0..127
    float s = 0.0f;
    if (e < EMB) {
#pragma unroll
        for (int c = 0; c < CTX; ++c) {
            const int idx = x[b * CTX + c];
            s += emb_v[idx * EMB + e];
        }
        s *= (1.0f / CTX);
        hf[b * EMB + e] = s;
    }
    hb[b * KP + e] = (e < EMB) ? f2bf(s) : (unsigned short)0;
}

// ---------------- fused bf16-MFMA GEMM + sigmoid row-sum ----------------
// block (bc, vy): v-tile [vy*128, +128), batch range [bc*512, +512) in 4 subtiles of 128.
// u-tile staged in LDS ONCE per block (the reuse fix); h-subtile staged per iteration.
__launch_bounds__(256, 3)
__global__ void k_neg(const unsigned short* __restrict__ hb,
                      const unsigned short* __restrict__ ub,
                      float* __restrict__ partial) {
    // strides padded to keep 16B alignment AND uniform bank spread for b128 frag reads:
    // us: 136 ush = 272 B = 68 dw (bank stride 4); hs: 72 ush = 144 B = 36 dw (bank stride 4)
    __shared__ unsigned short us[128][136];
    __shared__ unsigned short hs[128][72];
    __shared__ float red[2][128];

    const int t   = threadIdx.x;
    const int w   = t >> 6;         // wave 0..3
    const int L   = t & 63;
    const int c16 = L & 15;         // MFMA n/m lane index
    const int q   = L >> 4;         // MFMA quad
    const int wb  = (w & 1) * 64;   // wave b-offset in 128-tile
    const int wv  = (w >> 1) * 64;  // wave v-offset in 128-tile
    const int vy  = blockIdx.y;
    const int v0  = vy * 128;
    const int bbase = blockIdx.x * (BATCH / BC);  // 512 per chunk

    // ---- stage u tile once: 128 rows x 128 k (bf16, already padded/zeroed in ub) ----
#pragma unroll
    for (int i = 0; i < 8; ++i) {
        const int c  = i * 256 + t;         // 2048 16B chunks
        const int r  = c >> 4;
        const int kb = (c & 15) * 8;
        *(short8*)&us[r][kb] = *(const short8*)&ub[(v0 + r) * KP + kb];
    }
    __syncthreads();

#pragma unroll 1
    for (int bt = 0; bt < (BATCH / BC) / BT; ++bt) {   // 4 subtiles
        const int b0 = bbase + bt * BT;
        f32x4 acc[4][4];
#pragma unroll
        for (int mi = 0; mi < 4; ++mi)
#pragma unroll
            for (int ni = 0; ni < 4; ++ni) acc[mi][ni] = (f32x4)(0.0f);

#pragma unroll
        for (int kh = 0; kh < 2; ++kh) {               // two 64-wide K halves of h in LDS
            __syncthreads();
#pragma unroll
            for (int i = 0; i < 4; ++i) {              // stage h half: 128 rows x 64 k
                const int c  = i * 256 + t;
                const int r  = c >> 3;
                const int kb = (c & 7) * 8;
                *(short8*)&hs[r][kb] = *(const short8*)&hb[(b0 + r) * KP + kh * 64 + kb];
            }
            __syncthreads();
#pragma unroll
            for (int kcc = 0; kcc < 2; ++kcc) {        // two K=32 MFMA chunks
                const int ko = kcc * 32 + q * 8;
                short8 af[4], bf[4];
#pragma unroll
                for (int mi = 0; mi < 4; ++mi)
                    af[mi] = *(const short8*)&hs[wb + mi * 16 + c16][ko];
#pragma unroll
                for (int ni = 0; ni < 4; ++ni)
                    bf[ni] = *(const short8*)&us[wv + ni * 16 + c16][kh * 64 + ko];
#pragma unroll
                for (int mi = 0; mi < 4; ++mi)
#pragma unroll
                    for (int ni = 0; ni < 4; ++ni)
                        acc[mi][ni] = __builtin_amdgcn_mfma_f32_16x16x32_bf16(
                            af[mi], bf[ni], acc[mi][ni], 0, 0, 0);
            }
        }

        // ---- epilogue: p = sigmoid(-score) = 1/(1+exp(score)); sum over v ----
#pragma unroll
        for (int mi = 0; mi < 4; ++mi) {
            float ps[4] = {0.f, 0.f, 0.f, 0.f};
#pragma unroll
            for (int ni = 0; ni < 4; ++ni) {
                const int v = v0 + wv + ni * 16 + c16;
                if (v < VOCAB) {
#pragma unroll
                    for (int r = 0; r < 4; ++r)
                        ps[r] += __builtin_amdgcn_rcpf(1.0f + __expf(acc[mi][ni][r]));
                }
            }
#pragma unroll
            for (int r = 0; r < 4; ++r) {
                float p = ps[r];
#pragma unroll
                for (int off = 8; off; off >>= 1) p += __shfl_down(p, off, 16);
                if (c16 == 0) red[w >> 1][wb + mi * 16 + q * 4 + r] = p;
            }
        }
        __syncthreads();
        if (t < 128) partial[vy * BATCH + b0 + t] = red[0][t] + red[1][t];
        // next iteration's first __syncthreads orders red/hs reuse
    }
}

// ---------------- final: pos term + log(sum of partials) + mean ----------------
__global__ void k_final(const int* __restrict__ y, const float* __restrict__ hf,
                        const float* __restrict__ u, const float* __restrict__ partial,
                        float* __restrict__ out) {
    const int b = blockIdx.x * 64 + threadIdx.x;
    float ns = 0.0f;
    for (int vt = 0; vt < NVT; ++vt) ns += partial[vt * BATCH + b];

    const int yi = y[b];
    const float4* hp = (const float4*)&hf[b * EMB];
    const float4* up = (const float4*)&u[yi * EMB];
    float dot = 0.0f;
#pragma unroll
    for (int qq = 0; qq < EMB / 4; ++qq) {
        const float4 a = hp[qq];
        const float4 c = up[qq];
        dot += a.x * c.x + a.y * c.y + a.z * c.z + a.w * c.w;
    }
    const float pos = fmaxf(-dot, 0.0f) + log1pf(__expf(-fabsf(dot)));  // softplus(-dot)
    float val = pos + logf(ns);
#pragma unroll
    for (int off = 32; off; off >>= 1) val += __shfl_down(val, off, 64);
    if (threadIdx.x == 0) atomicAdd(out, val * (1.0f / BATCH));
}

extern "C" void kernel_launch(void* const* d_in, const int* in_sizes, int n_in,
                              void* d_out, int out_size, void* d_ws, size_t ws_size,
                              hipStream_t stream) {
    const int*   x     = (const int*)d_in[0];
    const int*   y     = (const int*)d_in[1];
    const float* emb_v = (const float*)d_in[2];
    const float* emb_u = (const float*)d_in[3];
    float* out = (float*)d_out;

    // workspace carve (17.4 MB total)
    float*          hf      = (float*)d_ws;                       // 2048*100 fp32
    float*          partial = hf + BATCH * EMB;                   // 391*2048 fp32
    unsigned short* hb      = (unsigned short*)(partial + NVT * BATCH);  // 2048*128 bf16
    unsigned short* ub      = hb + BATCH * KP;                    // 50048*128 bf16

    k_init <<<1, 64, 0, stream>>>(out);
    k_cvt_u<<<dim3(3128), dim3(256), 0, stream>>>(emb_u, ub);
    k_h    <<<dim3(BATCH), dim3(128), 0, stream>>>(x, emb_v, hf, hb);
    k_neg  <<<dim3(BC, NVT), dim3(256), 0, stream>>>(hb, ub, partial);
    k_final<<<dim3(BATCH / 64), dim3(64), 0, stream>>>(y, hf, emb_u, partial, out);
}

// Round 3
// 190.434 us; speedup vs baseline: 4.7092x; 1.0054x over previous
//
#include <hip/hip_runtime.h>
#include <math.h>

#define VOCAB 50000
#define EMB   100
#define KP    128      // K padded for MFMA
#define BATCH 2048
#define CTX   10

#define NVT   391      // 128-wide vocab tiles (391*128 = 50048)
#define BC    4        // batch chunks (grid.x); block covers 512 b in 4 subtiles
#define BT    128      // batch subtile

typedef __attribute__((ext_vector_type(8))) short short8;
typedef __attribute__((ext_vector_type(4))) float f32x4;

__device__ __forceinline__ unsigned short f2bf(float x) {
    union { float f; unsigned u; } v; v.f = x;
    unsigned r = (v.u + 0x7FFFu + ((v.u >> 16) & 1u)) >> 16;  // RNE
    return (unsigned short)r;
}

// ---------------- zero neg_sum[BATCH] and out ----------------
__global__ void k_init(float* __restrict__ neg_sum, float* __restrict__ out) {
    const int i = blockIdx.x * 256 + threadIdx.x;
    if (i < BATCH) neg_sum[i] = 0.0f;
    if (i == 0) out[0] = 0.0f;
}

// ---------------- emb_u fp32 [50000][100] -> bf16 [50048][128] zero-padded ----------------
__global__ void k_cvt_u(const float* __restrict__ u, unsigned short* __restrict__ ub) {
    const int c   = blockIdx.x * 256 + threadIdx.x;   // 800768 16B-chunks
    const int row = c >> 4;
    const int kb  = (c & 15) * 8;
    short8 o;
    if (row < VOCAB && kb + 8 <= EMB) {
        const float4* p = (const float4*)&u[row * EMB + kb];
        const float4 v0 = p[0], v1 = p[1];
        o[0] = (short)f2bf(v0.x); o[1] = (short)f2bf(v0.y);
        o[2] = (short)f2bf(v0.z); o[3] = (short)f2bf(v0.w);
        o[4] = (short)f2bf(v1.x); o[5] = (short)f2bf(v1.y);
        o[6] = (short)f2bf(v1.z); o[7] = (short)f2bf(v1.w);
    } else {
#pragma unroll
        for (int j = 0; j < 8; ++j) {
            const int k = kb + j;
            const float val = (row < VOCAB && k < EMB) ? u[row * EMB + k] : 0.0f;
            o[j] = (short)f2bf(val);
        }
    }
    *(short8*)&ub[row * KP + kb] = o;
}

// ---------------- h = mean of context embeddings; fp32 (pos term) + bf16 padded ----------------
__global__ void k_h(const int* __restrict__ x, const float* __restrict__ emb_v,
                    float* __restrict__ hf, unsigned short* __restrict__ hb) {
    const int b = blockIdx.x;
    const int e = threadIdx.x;  // 0..127
    float s = 0.0f;
    if (e < EMB) {
#pragma unroll
        for (int c = 0; c < CTX; ++c) {
            const int idx = x[b * CTX + c];
            s += emb_v[idx * EMB + e];
        }
        s *= (1.0f / CTX);
        hf[b * EMB + e] = s;
    }
    hb[b * KP + e] = (e < EMB) ? f2bf(s) : (unsigned short)0;
}

// ---------------- fused bf16-MFMA GEMM + sigmoid row-sum ----------------
// Transposed roles: A = u (m axis = v), B = h (n axis = b).
// D layout: col(lane&15) = b, row(q*4+reg) = v  -> v-sum is in-register + 2 shuffles.
// No LDS, no barriers: u-frags in registers (loaded once), h-frags from L2 per subtile.
__launch_bounds__(256, 2)
__global__ void k_neg(const unsigned short* __restrict__ hb,
                      const unsigned short* __restrict__ ub,
                      float* __restrict__ neg_sum) {
    const int t   = threadIdx.x;
    const int w   = t >> 6;          // wave 0..3
    const int L   = t & 63;
    const int c16 = L & 15;
    const int q   = L >> 4;
    const int wm  = (w & 1) * 64;    // wave v-offset within 128-tile
    const int wn  = (w >> 1) * 64;   // wave b-offset within 128-subtile
    const int v0  = blockIdx.y * 128;
    const int bbase = blockIdx.x * (BATCH / BC);   // 512 per chunk

    // ---- A-fragments (u): 16 x short8 = 64 VGPRs, loaded once, reused 4x ----
    short8 a_frag[4][4];   // [kc][mi]
#pragma unroll
    for (int kc = 0; kc < 4; ++kc)
#pragma unroll
        for (int mi = 0; mi < 4; ++mi)
            a_frag[kc][mi] = *(const short8*)&ub[(v0 + wm + mi * 16 + c16) * KP + kc * 32 + q * 8];

#pragma unroll 1
    for (int bt = 0; bt < (BATCH / BC) / BT; ++bt) {   // 4 subtiles of 128 b
        const int b0 = bbase + bt * BT;

        // ---- B-fragments (h) straight from global (hb is 512 KB, L2-hot) ----
        short8 b_frag[4][4];   // [kc][ni]
#pragma unroll
        for (int kc = 0; kc < 4; ++kc)
#pragma unroll
            for (int ni = 0; ni < 4; ++ni)
                b_frag[kc][ni] = *(const short8*)&hb[(b0 + wn + ni * 16 + c16) * KP + kc * 32 + q * 8];

        f32x4 acc[4][4];
#pragma unroll
        for (int mi = 0; mi < 4; ++mi)
#pragma unroll
            for (int ni = 0; ni < 4; ++ni) acc[mi][ni] = (f32x4)(0.0f);

#pragma unroll
        for (int kc = 0; kc < 4; ++kc)
#pragma unroll
            for (int mi = 0; mi < 4; ++mi)
#pragma unroll
                for (int ni = 0; ni < 4; ++ni)
                    acc[mi][ni] = __builtin_amdgcn_mfma_f32_16x16x32_bf16(
                        a_frag[kc][mi], b_frag[kc][ni], acc[mi][ni], 0, 0, 0);

        // ---- epilogue: sum_v sigmoid(-score) per b column ----
        // pairwise: 1/(1+ea) + 1/(1+eb) = (2+ea+eb) / ((1+ea)(1+eb))
#pragma unroll
        for (int ni = 0; ni < 4; ++ni) {
            float p = 0.0f;
#pragma unroll
            for (int mi = 0; mi < 4; ++mi) {
                const int vb = v0 + wm + mi * 16 + q * 4;  // v of reg 0 (uniform across c16)
#pragma unroll
                for (int pr = 0; pr < 2; ++pr) {
                    if (vb + pr * 2 < VOCAB) {   // VOCAB even: pairs never straddle
                        const float ea = __expf(acc[mi][ni][2 * pr + 0]);
                        const float eb = __expf(acc[mi][ni][2 * pr + 1]);
                        const float num = 2.0f + ea + eb;
                        const float den = (1.0f + ea) * (1.0f + eb);
                        p = fmaf(num, __builtin_amdgcn_rcpf(den), p);
                    }
                }
            }
            // fold the q dimension (v-groups live on lane strides of 16)
            p += __shfl_down(p, 32);
            p += __shfl_down(p, 16);
            if (L < 16) atomicAdd(&neg_sum[b0 + wn + ni * 16 + L], p);
        }
    }
}

// ---------------- final: pos term + log(neg_sum) + mean ----------------
__global__ void k_final(const int* __restrict__ y, const float* __restrict__ hf,
                        const float* __restrict__ u, const float* __restrict__ neg_sum,
                        float* __restrict__ out) {
    const int b = blockIdx.x * 64 + threadIdx.x;
    const int yi = y[b];
    const float4* hp = (const float4*)&hf[b * EMB];
    const float4* up = (const float4*)&u[yi * EMB];
    float dot = 0.0f;
#pragma unroll
    for (int qq = 0; qq < EMB / 4; ++qq) {
        const float4 a = hp[qq];
        const float4 c = up[qq];
        dot += a.x * c.x + a.y * c.y + a.z * c.z + a.w * c.w;
    }
    const float pos = fmaxf(-dot, 0.0f) + log1pf(__expf(-fabsf(dot)));  // softplus(-dot)
    float val = pos + logf(neg_sum[b]);
#pragma unroll
    for (int off = 32; off; off >>= 1) val += __shfl_down(val, off, 64);
    if (threadIdx.x == 0) atomicAdd(out, val * (1.0f / BATCH));
}

extern "C" void kernel_launch(void* const* d_in, const int* in_sizes, int n_in,
                              void* d_out, int out_size, void* d_ws, size_t ws_size,
                              hipStream_t stream) {
    const int*   x     = (const int*)d_in[0];
    const int*   y     = (const int*)d_in[1];
    const float* emb_v = (const float*)d_in[2];
    const float* emb_u = (const float*)d_in[3];
    float* out = (float*)d_out;

    // workspace carve (~14.2 MB)
    float*          hf      = (float*)d_ws;                      // 2048*100 fp32
    float*          neg_sum = hf + BATCH * EMB;                  // 2048 fp32
    unsigned short* hb      = (unsigned short*)(neg_sum + BATCH);// 2048*128 bf16
    unsigned short* ub      = hb + BATCH * KP;                   // 50048*128 bf16

    k_init <<<dim3((BATCH + 255) / 256), dim3(256), 0, stream>>>(neg_sum, out);
    k_cvt_u<<<dim3(3128), dim3(256), 0, stream>>>(emb_u, ub);
    k_h    <<<dim3(BATCH), dim3(128), 0, stream>>>(x, emb_v, hf, hb);
    k_neg  <<<dim3(BC, NVT), dim3(256), 0, stream>>>(hb, ub, neg_sum);
    k_final<<<dim3(BATCH / 64), dim3(64), 0, stream>>>(y, hf, emb_u, neg_sum, out);
}